// Round 3
// baseline (1155.653 us; speedup 1.0000x reference)
//
#include <hip/hip_runtime.h>
#include <stdint.h>
#include <math.h>

// Round 9: lane=row fold (kills the random-k LDS gather of the 786.5µs
// baseline) + 4-column interleaved fold for ILP under 1-wave/SIMD occupancy.
//
// Fold: block = 64 batch rows; xT[k][row] LDS tile, pad 65 (conflict-free
// b32 reads AND staging writes). Weights wave-uniform per column: coalesced
// 64-wide uint2 load, v_readlane broadcast. 4 columns folded jointly with
// shared bound cmax=max(cnt): pairsA is zero-padded to MAXE, and fmaf(+/-0,
// x, a)==a exactly (a is never -0: starts +0, RNE gives +0 on exact cancel)
// -> padded steps are bit-exact no-ops, no masking needed. Ascending-k f32
// fold order preserved -> bit-identical y to the validated kernel.
// y -> out row-major (64B/lane chunks, L2-merged). select_kernel re-reads
// out and applies the VALIDATED bias+boost+radix-top-k verbatim, in place.
//
// Predicted: fold ~140-170us (LDS conflicts ~0, 4 indep FMA chains, 8 LDS
// reads in flight), select ~200-250us (~50% HBM), total ~380-440 vs 786.5.

#define BATCH 16384
#define K_DIM 512
#define N_DIM 4096
#define RPB 4
#define MAXE 64
#define ROWS_A 64
#define XPAD 65   // padded xT row stride in floats: conflict-free reads+writes

typedef float f32x4 __attribute__((ext_vector_type(4)));
typedef unsigned int u32;

#define RDL(v, l) __builtin_amdgcn_readlane((int)(v), (l))

// ---------- boost table ----------
__global__ void boost_kernel(const float* __restrict__ duty,
                             const int* __restrict__ kptr,
                             float* __restrict__ boost) {
  const int j = blockIdx.x * blockDim.x + threadIdx.x;
  if (j < N_DIM) {
    const float td = (float)((double)kptr[0] / (double)N_DIM);
    const float arg = 0.5f * (td - duty[j]);      // f32 ops, as reference
    boost[j] = (float)exp((double)arg);           // correctly-rounded f32 exp
  }
}

// ---------- compress: per-column nonzeros, ascending k ----------
__global__ __launch_bounds__(256) void compress_kernel(
    const float* __restrict__ W, const float* __restrict__ mask,
    unsigned short* __restrict__ cIdx, float* __restrict__ cVal,
    int* __restrict__ cnt) {
  const int j = blockIdx.x * 4 + (threadIdx.x >> 6);  // one wave per column
  const int lane = threadIdx.x & 63;
  if (j >= N_DIM) return;
  const float* mr = mask + (size_t)j * K_DIM;
  const float* wr = W + (size_t)j * K_DIM;
  int base = 0;
#pragma unroll
  for (int c = 0; c < K_DIM / 64; ++c) {
    const int k = c * 64 + lane;
    const bool act = (mr[k] != 0.0f);
    const unsigned long long bal = __ballot(act);
    const int pos = __popcll(bal & ((1ull << lane) - 1ull));
    if (act && base + pos < MAXE) {
      cIdx[(size_t)j * MAXE + base + pos] = (unsigned short)k;
      cVal[(size_t)j * MAXE + base + pos] = wr[k];   // mask==1 -> exact
    }
    base += (int)__popcll(bal);
  }
  if (lane == 0) cnt[j] = base < MAXE ? base : MAXE;
}

// ---------- pack (k*XPAD, w-bits) pairs, zero-padded to MAXE ----------
__global__ __launch_bounds__(256) void fillA_kernel(
    const unsigned short* __restrict__ cIdx, const float* __restrict__ cVal,
    const int* __restrict__ cnt, uint2* __restrict__ pairsA) {
  const int idx = blockIdx.x * 256 + threadIdx.x;  // 0 .. 4096*64-1
  const int j = idx >> 6;
  const int e = idx & 63;
  uint2 pr;
  if (e < cnt[j]) {
    pr.x = (u32)cIdx[(size_t)j * MAXE + e] * (u32)XPAD;  // xT element offset
    pr.y = __float_as_uint(cVal[(size_t)j * MAXE + e]);
  } else {
    pr.x = 0u; pr.y = 0u;                                // exact fold no-op
  }
  pairsA[idx] = pr;
}

// ---------- fold: lane=row, wave-uniform weights, 4-col interleave ----------
__global__ __launch_bounds__(256) void fold_kernel(
    const float* __restrict__ x, const uint2* __restrict__ pairsA,
    const int* __restrict__ cnt, float* __restrict__ y) {
  __shared__ float xT[K_DIM * XPAD];          // 512*65*4 = 133,120 B
  const int tid = threadIdx.x;
  const int lane = tid & 63;
  const int wave = tid >> 6;
  const int row0 = blockIdx.x * ROWS_A;

  // stage xT[k*XPAD + row] = x[row0+row][k]; coalesced global (k tid-minor),
  // LDS write stride 65 floats -> bank stride 1 -> conflict-free
#pragma unroll 1
  for (int i = 0; i < (ROWS_A * K_DIM) / 256; ++i) {   // 128 iters
    const int flat = i * 256 + tid;
    const int row = flat >> 9;                         // /512
    const int k = flat & (K_DIM - 1);
    xT[k * XPAD + row] = x[(size_t)(row0 + row) * K_DIM + k];
  }
  __syncthreads();

  const int jbase = wave * (N_DIM / 4);                // 1024 columns per wave

#pragma unroll 1
  for (int g = 0; g < (N_DIM / 4) / 16; ++g) {         // 64 groups of 16 cols
    float acc[16];
#pragma unroll 1
    for (int c4 = 0; c4 < 4; ++c4) {
      const int j0 = jbase + g * 16 + c4 * 4;
      // 64-wide coalesced fetch: lane l holds entry l of each column
      const uint2 ev0 = pairsA[(size_t)(j0 + 0) * MAXE + lane];
      const uint2 ev1 = pairsA[(size_t)(j0 + 1) * MAXE + lane];
      const uint2 ev2 = pairsA[(size_t)(j0 + 2) * MAXE + lane];
      const uint2 ev3 = pairsA[(size_t)(j0 + 3) * MAXE + lane];
      const int c0 = __builtin_amdgcn_readfirstlane(cnt[j0 + 0]);
      const int c1 = __builtin_amdgcn_readfirstlane(cnt[j0 + 1]);
      const int c2 = __builtin_amdgcn_readfirstlane(cnt[j0 + 2]);
      const int c3 = __builtin_amdgcn_readfirstlane(cnt[j0 + 3]);
      int cmax = c0 > c1 ? c0 : c1;
      cmax = c2 > cmax ? c2 : cmax;
      cmax = c3 > cmax ? c3 : cmax;
      float a0 = 0.0f, a1 = 0.0f, a2 = 0.0f, a3 = 0.0f;
      int e = 0;
      // 2 entry-steps x 4 columns: 8 independent LDS reads in flight,
      // 4 independent fma chains; short columns run exact no-op padding
      for (; e + 2 <= cmax; e += 2) {
        const float x00 = xT[RDL(ev0.x, e) + lane];
        const float x10 = xT[RDL(ev1.x, e) + lane];
        const float x20 = xT[RDL(ev2.x, e) + lane];
        const float x30 = xT[RDL(ev3.x, e) + lane];
        const float x01 = xT[RDL(ev0.x, e + 1) + lane];
        const float x11 = xT[RDL(ev1.x, e + 1) + lane];
        const float x21 = xT[RDL(ev2.x, e + 1) + lane];
        const float x31 = xT[RDL(ev3.x, e + 1) + lane];
        a0 = fmaf(__uint_as_float((u32)RDL(ev0.y, e)), x00, a0);
        a1 = fmaf(__uint_as_float((u32)RDL(ev1.y, e)), x10, a1);
        a2 = fmaf(__uint_as_float((u32)RDL(ev2.y, e)), x20, a2);
        a3 = fmaf(__uint_as_float((u32)RDL(ev3.y, e)), x30, a3);
        a0 = fmaf(__uint_as_float((u32)RDL(ev0.y, e + 1)), x01, a0);
        a1 = fmaf(__uint_as_float((u32)RDL(ev1.y, e + 1)), x11, a1);
        a2 = fmaf(__uint_as_float((u32)RDL(ev2.y, e + 1)), x21, a2);
        a3 = fmaf(__uint_as_float((u32)RDL(ev3.y, e + 1)), x31, a3);
      }
      if (e < cmax) {
        const float x00 = xT[RDL(ev0.x, e) + lane];
        const float x10 = xT[RDL(ev1.x, e) + lane];
        const float x20 = xT[RDL(ev2.x, e) + lane];
        const float x30 = xT[RDL(ev3.x, e) + lane];
        a0 = fmaf(__uint_as_float((u32)RDL(ev0.y, e)), x00, a0);
        a1 = fmaf(__uint_as_float((u32)RDL(ev1.y, e)), x10, a1);
        a2 = fmaf(__uint_as_float((u32)RDL(ev2.y, e)), x20, a2);
        a3 = fmaf(__uint_as_float((u32)RDL(ev3.y, e)), x30, a3);
      }
      acc[c4 * 4 + 0] = a0;
      acc[c4 * 4 + 1] = a1;
      acc[c4 * 4 + 2] = a2;
      acc[c4 * 4 + 3] = a3;
    }
    // write y[row0+lane][jbase + g*16 .. +15]: 64B aligned per lane
    float* yp = y + (size_t)(row0 + lane) * N_DIM + jbase + g * 16;
    *(f32x4*)(yp)      = (f32x4){acc[0],  acc[1],  acc[2],  acc[3]};
    *(f32x4*)(yp + 4)  = (f32x4){acc[4],  acc[5],  acc[6],  acc[7]};
    *(f32x4*)(yp + 8)  = (f32x4){acc[8],  acc[9],  acc[10], acc[11]};
    *(f32x4*)(yp + 12) = (f32x4){acc[12], acc[13], acc[14], acc[15]};
  }
}

// ---------- select: validated exact radix top-k, in place on out ----------
__global__ __launch_bounds__(256) void select_kernel(
    const float* __restrict__ bvec, const float* __restrict__ boost,
    const int* __restrict__ kptr, float* __restrict__ out) {
  __shared__ u32 hist[256];
  __shared__ u32 s_prefix, s_kk;
  const int tid = threadIdx.x;
  const int row0 = blockIdx.x * RPB;
  const int kk0 = kptr[0];

#pragma unroll 1
  for (int r = 0; r < RPB; ++r) {
    __syncthreads();                                // protects s_* across rows
    float* orow = out + (size_t)(row0 + r) * N_DIM;

    float y[16], bl[16];
    u32 key[16];
#pragma unroll
    for (int u = 0; u < 16; ++u) {
      const int j = u * 256 + tid;
      y[u] = orow[j] + bvec[j];                     // single f32 add
      bl[u] = boost[j];
      const float t = y[u] * bl[u];                 // single f32 mult
      const u32 v = __float_as_uint(t);
      key[u] = (v & 0x80000000u) ? ~v : (v | 0x80000000u);
    }
    if (tid == 0) { s_prefix = 0u; s_kk = (u32)kk0; }
    __syncthreads();

#pragma unroll 1
    for (int round = 0; round < 4; ++round) {
      const int shift = 24 - 8 * round;
      const u32 prefix = s_prefix;
      const u32 kk = s_kk;
      const u32 himask = round ? (0xFFFFFFFFu << (32 - 8 * round)) : 0u;
      hist[tid] = 0u;
      __syncthreads();
#pragma unroll
      for (int u = 0; u < 16; ++u)
        if ((key[u] & himask) == prefix)
          atomicAdd(&hist[(key[u] >> shift) & 255u], 1u);
      __syncthreads();
      if (tid < 64) {                               // wave 0: suffix scan
        const int l = tid;
        const u32 h0 = hist[l * 4], h1 = hist[l * 4 + 1];
        const u32 h2 = hist[l * 4 + 2], h3 = hist[l * 4 + 3];
        const u32 s3 = h3, s2 = h2 + s3, s1 = h1 + s2, s0 = h0 + s1;
        u32 t = s0;
#pragma unroll
        for (int off = 1; off < 64; off <<= 1) {
          const u32 v = __shfl_down(t, off, 64);
          if (l + off < 64) t += v;
        }
        const u32 Eab = t - s0;                     // lanes strictly above
        const u32 S[5] = {Eab + s0, Eab + s1, Eab + s2, Eab + s3, Eab};
#pragma unroll
        for (int i = 0; i < 4; ++i)
          if (S[i] >= kk && S[i + 1] < kk) {
            s_prefix = prefix | ((u32)(l * 4 + i) << shift);
            s_kk = kk - S[i + 1];
          }
      }
      __syncthreads();
    }
    const u32 tkey = s_prefix;

#pragma unroll
    for (int u = 0; u < 16; ++u)
      orow[u * 256 + tid] = (key[u] >= tkey) ? y[u] : 0.0f;
  }
}

extern "C" void kernel_launch(void* const* d_in, const int* in_sizes, int n_in,
                              void* d_out, int out_size, void* d_ws, size_t ws_size,
                              hipStream_t stream) {
  const float* x     = (const float*)d_in[0];
  const float* W     = (const float*)d_in[1];
  const float* bvec  = (const float*)d_in[2];
  const float* wmask = (const float*)d_in[3];
  const float* duty  = (const float*)d_in[4];
  const int* kptr    = (const int*)d_in[5];
  float* out = (float*)d_out;

  uint8_t* ws = (uint8_t*)d_ws;
  unsigned short* cIdx = (unsigned short*)(ws);                 // 512 KiB
  float* cVal          = (float*)(ws + (1u << 20));             // 1 MiB
  int* cnt             = (int*)(ws + (2u << 20));               // 16 KiB
  float* boost         = (float*)(ws + (2u << 20) + (64u << 10));
  uint2* pairsA        = (uint2*)(ws + (4u << 20));             // 2 MiB

  boost_kernel<<<16, 256, 0, stream>>>(duty, kptr, boost);
  compress_kernel<<<N_DIM / 4, 256, 0, stream>>>(W, wmask, cIdx, cVal, cnt);
  fillA_kernel<<<(N_DIM * MAXE) / 256, 256, 0, stream>>>(cIdx, cVal, cnt, pairsA);
  fold_kernel<<<BATCH / ROWS_A, 256, 0, stream>>>(x, pairsA, cnt, out);
  select_kernel<<<BATCH / RPB, 256, 0, stream>>>(bvec, boost, kptr, out);
}

// Round 4
// 743.337 us; speedup vs baseline: 1.5547x; 1.5547x over previous
//
#include <hip/hip_runtime.h>
#include <stdint.h>
#include <math.h>

// Round 10: occupancy + scalar-operand fold + write-granule fix + select v2.
//
// r9 counters: fold 760us, BANK_CONFLICT=0 (layout works), Occupancy 12.1%
// (1 wave/SIMD: 133KB LDS + 256-thr block), VALUBusy 40%, 59 cyc/entry
// latency-exposed; WRITE_SIZE 654MB vs 256 ideal (64B/lane stores into
// 128B granules).
// Fixes:
//  - 1024-thr block: 16 waves share one xT tile (256 cols/wave) -> 4 w/SIMD.
//  - (k,w) entries are wave-uniform -> uniform s_load into SGPRs (indices
//    made provably uniform via readfirstlane(wave)); per entry: v_add +
//    v_fmac(sgpr w) + ds_read_b32 = 2 VALU (was 4 w/ readlanes). VGPR ~50
//    -> fits 16 waves (<=128).
//  - acc[32], store 128B contiguous per lane -> amplification 1.0.
//  - select: j = tid*16+u remap (selection is index-agnostic) -> f32x4
//    loads/stores; per-wave hist4[4][256] + merge -> 4x less atomic serial.
// Numerics unchanged: ascending-k f32 fmaf fold (zero-pad = exact no-op:
// a never -0), bias add, boost mult, monotone-key radix top-k, ties >=.

#define BATCH 16384
#define K_DIM 512
#define N_DIM 4096
#define RPB 4
#define MAXE 64
#define ROWS_A 64
#define XPAD 65   // xT row stride: conflict-free b32 reads AND staging writes

typedef float f32x4 __attribute__((ext_vector_type(4)));
typedef unsigned int u32;

// ---------- boost table ----------
__global__ void boost_kernel(const float* __restrict__ duty,
                             const int* __restrict__ kptr,
                             float* __restrict__ boost) {
  const int j = blockIdx.x * blockDim.x + threadIdx.x;
  if (j < N_DIM) {
    const float td = (float)((double)kptr[0] / (double)N_DIM);
    const float arg = 0.5f * (td - duty[j]);      // f32 ops, as reference
    boost[j] = (float)exp((double)arg);           // correctly-rounded f32 exp
  }
}

// ---------- compress: per-column nonzeros, ascending k ----------
__global__ __launch_bounds__(256) void compress_kernel(
    const float* __restrict__ W, const float* __restrict__ mask,
    unsigned short* __restrict__ cIdx, float* __restrict__ cVal,
    int* __restrict__ cnt) {
  const int j = blockIdx.x * 4 + (threadIdx.x >> 6);  // one wave per column
  const int lane = threadIdx.x & 63;
  if (j >= N_DIM) return;
  const float* mr = mask + (size_t)j * K_DIM;
  const float* wr = W + (size_t)j * K_DIM;
  int base = 0;
#pragma unroll
  for (int c = 0; c < K_DIM / 64; ++c) {
    const int k = c * 64 + lane;
    const bool act = (mr[k] != 0.0f);
    const unsigned long long bal = __ballot(act);
    const int pos = __popcll(bal & ((1ull << lane) - 1ull));
    if (act && base + pos < MAXE) {
      cIdx[(size_t)j * MAXE + base + pos] = (unsigned short)k;
      cVal[(size_t)j * MAXE + base + pos] = wr[k];   // mask==1 -> exact
    }
    base += (int)__popcll(bal);
  }
  if (lane == 0) cnt[j] = base < MAXE ? base : MAXE;
}

// ---------- pack (k*XPAD, w-bits) pairs, zero-padded to MAXE ----------
__global__ __launch_bounds__(256) void fillA_kernel(
    const unsigned short* __restrict__ cIdx, const float* __restrict__ cVal,
    const int* __restrict__ cnt, uint2* __restrict__ pairsA) {
  const int idx = blockIdx.x * 256 + threadIdx.x;  // 0 .. 4096*64-1
  const int j = idx >> 6;
  const int e = idx & 63;
  uint2 pr;
  if (e < cnt[j]) {
    pr.x = (u32)cIdx[(size_t)j * MAXE + e] * (u32)XPAD;  // xT element offset
    pr.y = __float_as_uint(cVal[(size_t)j * MAXE + e]);
  } else {
    pr.x = 0u; pr.y = 0u;                                // exact fold no-op
  }
  pairsA[idx] = pr;
}

// ---------- fold: 16 waves/tile, scalar (k,w) operands ----------
__global__ __launch_bounds__(1024, 1) void fold_kernel(
    const float* __restrict__ x, const uint2* __restrict__ pairsA,
    const int* __restrict__ cnt, float* __restrict__ y) {
  __shared__ float xT[K_DIM * XPAD];          // 512*65*4 = 133,120 B
  const int tid = threadIdx.x;
  const int lane = tid & 63;
  const int wave = __builtin_amdgcn_readfirstlane(tid >> 6);  // 0..15 uniform
  const int row0 = blockIdx.x * ROWS_A;

  // stage xT[k*XPAD + row] = x[row0+row][k]; k tid-minor -> coalesced global,
  // LDS bank stride 1 -> 2-way (free)
#pragma unroll 1
  for (int i = 0; i < (ROWS_A * K_DIM) / 1024; ++i) {  // 32 iters
    const int flat = i * 1024 + tid;
    const int row = flat >> 9;                         // /512
    const int k = flat & (K_DIM - 1);
    xT[k * XPAD + row] = x[(size_t)(row0 + row) * K_DIM + k];
  }
  __syncthreads();

  const int jbase = wave * (N_DIM / 16);               // 256 cols per wave

#pragma unroll 1
  for (int g = 0; g < 8; ++g) {                        // 8 groups of 32 cols
    float acc[32];
#pragma unroll
    for (int q = 0; q < 32; ++q) acc[q] = 0.0f;

#pragma unroll
    for (int c4 = 0; c4 < 8; ++c4) {                   // FULL unroll: static acc idx
      const int j0 = jbase + g * 32 + c4 * 4;
      const int4 cn = *(const int4*)(cnt + j0);        // uniform -> s_load
      int cmax = cn.x > cn.y ? cn.x : cn.y;
      cmax = cn.z > cmax ? cn.z : cmax;
      cmax = cn.w > cmax ? cn.w : cmax;
      const uint2* p0 = pairsA + (size_t)(j0 + 0) * MAXE;
      const uint2* p1 = pairsA + (size_t)(j0 + 1) * MAXE;
      const uint2* p2 = pairsA + (size_t)(j0 + 2) * MAXE;
      const uint2* p3 = pairsA + (size_t)(j0 + 3) * MAXE;
      float a0 = 0.0f, a1 = 0.0f, a2 = 0.0f, a3 = 0.0f;
      int e = 0;
#pragma unroll 1
      for (; e + 4 <= cmax; e += 4) {                  // 16 entries in flight
#pragma unroll
        for (int q = 0; q < 4; ++q) {
          const uint2 e0 = p0[e + q];                  // uniform s_load_dwordx2
          const uint2 e1 = p1[e + q];
          const uint2 e2 = p2[e + q];
          const uint2 e3 = p3[e + q];
          a0 = fmaf(__uint_as_float(e0.y), xT[e0.x + lane], a0);
          a1 = fmaf(__uint_as_float(e1.y), xT[e1.x + lane], a1);
          a2 = fmaf(__uint_as_float(e2.y), xT[e2.x + lane], a2);
          a3 = fmaf(__uint_as_float(e3.y), xT[e3.x + lane], a3);
        }
      }
#pragma unroll 1
      for (; e < cmax; ++e) {                          // <=3 remainder steps
        const uint2 e0 = p0[e];
        const uint2 e1 = p1[e];
        const uint2 e2 = p2[e];
        const uint2 e3 = p3[e];
        a0 = fmaf(__uint_as_float(e0.y), xT[e0.x + lane], a0);
        a1 = fmaf(__uint_as_float(e1.y), xT[e1.x + lane], a1);
        a2 = fmaf(__uint_as_float(e2.y), xT[e2.x + lane], a2);
        a3 = fmaf(__uint_as_float(e3.y), xT[e3.x + lane], a3);
      }
      acc[c4 * 4 + 0] = a0;
      acc[c4 * 4 + 1] = a1;
      acc[c4 * 4 + 2] = a2;
      acc[c4 * 4 + 3] = a3;
    }

    // 128B contiguous per lane -> full HBM write granules (no amplification)
    float* yp = y + (size_t)(row0 + lane) * N_DIM + jbase + g * 32;
#pragma unroll
    for (int q = 0; q < 8; ++q)
      *(f32x4*)(yp + q * 4) =
          (f32x4){acc[q * 4], acc[q * 4 + 1], acc[q * 4 + 2], acc[q * 4 + 3]};
  }
}

// ---------- select v2: vectorized, per-wave histograms ----------
__global__ __launch_bounds__(256) void select_kernel(
    const float* __restrict__ bvec, const float* __restrict__ boost,
    const int* __restrict__ kptr, float* __restrict__ out) {
  __shared__ u32 hist4[4 * 256];
  __shared__ u32 hist[256];
  __shared__ u32 s_prefix, s_kk;
  const int tid = threadIdx.x;
  const int wave = tid >> 6;
  const int row0 = blockIdx.x * RPB;
  const int kk0 = kptr[0];

#pragma unroll 1
  for (int r = 0; r < RPB; ++r) {
    __syncthreads();                                // protects s_* across rows
    float* orow = out + (size_t)(row0 + r) * N_DIM;

    // thread owns cols [tid*16, tid*16+16): f32x4 loads, 64B/lane contiguous
    float yv[16];
    u32 key[16];
    const f32x4* yp = (const f32x4*)orow + tid * 4;
    const f32x4* bp = (const f32x4*)bvec + tid * 4;
    const f32x4* gp = (const f32x4*)boost + tid * 4;
#pragma unroll
    for (int v = 0; v < 4; ++v) {
      const f32x4 a = yp[v], b = bp[v], c = gp[v];
#pragma unroll
      for (int q = 0; q < 4; ++q) {
        const float yy = a[q] + b[q];               // single f32 add
        const float t = yy * c[q];                  // single f32 mult
        const u32 u = __float_as_uint(t);
        yv[v * 4 + q] = yy;
        key[v * 4 + q] = (u & 0x80000000u) ? ~u : (u | 0x80000000u);
      }
    }
    if (tid == 0) { s_prefix = 0u; s_kk = (u32)kk0; }

#pragma unroll 1
    for (int round = 0; round < 4; ++round) {
      const int shift = 24 - 8 * round;
      const u32 himask = round ? (0xFFFFFFFFu << (32 - 8 * round)) : 0u;
      hist4[tid] = 0u; hist4[tid + 256] = 0u;
      hist4[tid + 512] = 0u; hist4[tid + 768] = 0u;
      __syncthreads();                              // covers reset + zeroing
      const u32 prefix = s_prefix;
      const u32 kk = s_kk;
#pragma unroll
      for (int u2 = 0; u2 < 16; ++u2)
        if ((key[u2] & himask) == prefix)
          atomicAdd(&hist4[wave * 256 + ((key[u2] >> shift) & 255u)], 1u);
      __syncthreads();
      hist[tid] = hist4[tid] + hist4[tid + 256] +
                  hist4[tid + 512] + hist4[tid + 768];
      __syncthreads();
      if (tid < 64) {                               // wave 0: suffix scan
        const int l = tid;
        const u32 h0 = hist[l * 4], h1 = hist[l * 4 + 1];
        const u32 h2 = hist[l * 4 + 2], h3 = hist[l * 4 + 3];
        const u32 s3 = h3, s2 = h2 + s3, s1 = h1 + s2, s0 = h0 + s1;
        u32 t = s0;
#pragma unroll
        for (int off = 1; off < 64; off <<= 1) {
          const u32 v = __shfl_down(t, off, 64);
          if (l + off < 64) t += v;
        }
        const u32 Eab = t - s0;                     // lanes strictly above
        const u32 S[5] = {Eab + s0, Eab + s1, Eab + s2, Eab + s3, Eab};
#pragma unroll
        for (int i = 0; i < 4; ++i)
          if (S[i] >= kk && S[i + 1] < kk) {
            s_prefix = prefix | ((u32)(l * 4 + i) << shift);
            s_kk = kk - S[i + 1];
          }
      }
      __syncthreads();
    }
    const u32 tkey = s_prefix;

    f32x4* op = (f32x4*)orow + tid * 4;
#pragma unroll
    for (int v = 0; v < 4; ++v) {
      f32x4 o;
#pragma unroll
      for (int q = 0; q < 4; ++q)
        o[q] = (key[v * 4 + q] >= tkey) ? yv[v * 4 + q] : 0.0f;
      op[v] = o;
    }
  }
}

extern "C" void kernel_launch(void* const* d_in, const int* in_sizes, int n_in,
                              void* d_out, int out_size, void* d_ws, size_t ws_size,
                              hipStream_t stream) {
  const float* x     = (const float*)d_in[0];
  const float* W     = (const float*)d_in[1];
  const float* bvec  = (const float*)d_in[2];
  const float* wmask = (const float*)d_in[3];
  const float* duty  = (const float*)d_in[4];
  const int* kptr    = (const int*)d_in[5];
  float* out = (float*)d_out;

  uint8_t* ws = (uint8_t*)d_ws;
  unsigned short* cIdx = (unsigned short*)(ws);                 // 512 KiB
  float* cVal          = (float*)(ws + (1u << 20));             // 1 MiB
  int* cnt             = (int*)(ws + (2u << 20));               // 16 KiB
  float* boost         = (float*)(ws + (2u << 20) + (64u << 10));
  uint2* pairsA        = (uint2*)(ws + (4u << 20));             // 2 MiB

  boost_kernel<<<16, 256, 0, stream>>>(duty, kptr, boost);
  compress_kernel<<<N_DIM / 4, 256, 0, stream>>>(W, wmask, cIdx, cVal, cnt);
  fillA_kernel<<<(N_DIM * MAXE) / 256, 256, 0, stream>>>(cIdx, cVal, cnt, pairsA);
  fold_kernel<<<BATCH / ROWS_A, 1024, 0, stream>>>(x, pairsA, cnt, out);
  select_kernel<<<BATCH / RPB, 256, 0, stream>>>(bvec, boost, kptr, out);
}